// Round 1
// 697.515 us; speedup vs baseline: 1.4705x; 1.4705x over previous
//
#include <hip/hip_runtime.h>
#include <math.h>

#define NPTS 4096
#define KNN 16
#define LN_EPS 1e-5f

// KNN filter+replay tuning
#define BOOT 64    // candidates processed with the direct r17 path (fills ld, tightens thr)
#define CAP  32    // per-lane LDS buffer slots
#define TRIG 24    // replay trigger: any lane with cnt >= TRIG after a group (max group add = 8, so writes stay < CAP)

// ---------------------------------------------------------------------------
// FROZEN ORACLE (r17 PASS, r19 falsified stable-top16): np's neighbor sets
// are reproduced by the r17 SERIAL algorithm exactly:
//   d2: sq=(x2+y2)+z2 seq; dot=fma(z,z',fma(y,y',x*x')); d2=(sqn+sqm)-(2*dot)
//   selection: ascending-j scan, admission `d2 < ld[15]` (strict, d2-only),
//   16-deep displaced-carry insert chain comparing d2 ONLY.
// The chain's equal-d2 scramble is part of the oracle. DO NOT modify
// admission/insert semantics.
//
// r21 (this round): filter + EXACT replay. Phase A computes the verbatim d2
// and buffers (d2,j) per lane against a STALE threshold thr = ld[15]-at-last-
// replay. Since ld[15] is non-increasing, thr >= ld[15]-exact at any later j,
// so the buffer is a SUPERSET of serial admissions. Replay pops each lane's
// buffer in ascending-j order and re-applies the exact strict admission
// `dd < ld[15]` + the verbatim chain => (ld,lj) state evolution is
// BIT-IDENTICAL to r17 (including equal-d2 scramble and final order, which
// fuse's fp accumulation order depends on). This removes the wave-serialized
// chain entry that fired on ~2400/4096 candidates (any-of-64-lanes admission).
// ---------------------------------------------------------------------------

__global__ __launch_bounds__(256) void proj3_kernel(
    const float* __restrict__ x, const float* __restrict__ Wq,
    const float* __restrict__ Wk, const float* __restrict__ Wv,
    float* __restrict__ qf, float* __restrict__ kf, float* __restrict__ vf) {
  int g = blockIdx.x * 256 + threadIdx.x;
  int r = g >> 6, c = g & 63;
  float sq = 0.f, sk = 0.f, sv = 0.f;
  for (int i = 0; i < 64; ++i) {
    float xv = x[r*64 + i];
    sq += xv * Wq[i*64 + c];
    sk += xv * Wk[i*64 + c];
    sv += xv * Wv[i*64 + c];
  }
  qf[g] = sq; kf[g] = sk; vf[g] = sv;
}

// Verbatim r17 displaced-carry insert chain (frozen oracle — do not touch).
#define INSERT_CHAIN(DD, JJ)                                          \
  do {                                                                \
    float dd = (DD); int jj = (JJ);                                   \
    _Pragma("unroll")                                                 \
    for (int v = 0; v < 16; ++v) {                                    \
      bool sw = dd < ld[v];                                           \
      float nd = sw ? dd : ld[v]; float td = sw ? ld[v] : dd;         \
      int   nj = sw ? jj : lj[v]; int   tj = sw ? lj[v] : jj;         \
      ld[v] = nd; lj[v] = nj; dd = td; jj = tj;                       \
    }                                                                 \
  } while (0)

// Pop this lane's buffered candidates in ascending-j (push) order, applying
// the EXACT admission check against the true evolving ld[15]. Single-wave
// block => no __syncthreads needed (same-lane LDS RAW handled by lgkmcnt).
#define REPLAY()                                                      \
  do {                                                                \
    for (int i = 0; ; ++i) {                                          \
      unsigned long long alive = __ballot(i < cnt);                   \
      if (!alive) break;                                              \
      if (i < cnt) {                                                  \
        float dd0 = s_buf[i*128 + bo];                                \
        int   jj0 = __float_as_int(s_buf[i*128 + bo + 1]);            \
        if (dd0 < ld[15]) INSERT_CHAIN(dd0, jj0);                     \
      }                                                               \
    }                                                                 \
    cnt = 0; thr = ld[15];                                            \
  } while (0)

__global__ __launch_bounds__(64) void knn_filter_replay_kernel(
    const float* __restrict__ pos, int* __restrict__ idx_out) {
  __shared__ __align__(16) float4 s_p[NPTS];       // 64 KB point cache (x,y,z,sq)
  __shared__ __align__(16) float  s_buf[CAP*128];  // 16 KB: slot i, lane t -> (d2,j) at i*128 + 2t
  int tid = threadIdx.x, b = blockIdx.y;
  const float* pb = pos + b*NPTS*3;
  for (int j = tid; j < NPTS; j += 64) {
    float px = pb[j*3+0], py = pb[j*3+1], pz = pb[j*3+2];
    float sq = __fadd_rn(__fadd_rn(__fmul_rn(px,px), __fmul_rn(py,py)),
                         __fmul_rn(pz,pz));
    s_p[j] = make_float4(px, py, pz, sq);
  }
  __syncthreads();
  int n = blockIdx.x * 64 + tid;
  float4 qp = s_p[n];
  float qx = qp.x, qy = qp.y, qz = qp.z, sqn = qp.w;
  float ld[16]; int lj[16];
#pragma unroll
  for (int u = 0; u < 16; ++u) { ld[u] = INFINITY; lj[u] = 0x7fffffff; }

  // --- bootstrap: first BOOT candidates via the direct r17 path (verbatim) ---
  for (int s = 0; s < BOOT; s += 8) {
    float4 p[8];
#pragma unroll
    for (int u = 0; u < 8; ++u) p[u] = s_p[s + u];
    float d2v[8];
#pragma unroll
    for (int u = 0; u < 8; ++u) {
      float acc = __fmul_rn(qx, p[u].x);
      acc = __fmaf_rn(qy, p[u].y, acc);
      acc = __fmaf_rn(qz, p[u].z, acc);
      d2v[u] = __fsub_rn(__fadd_rn(sqn, p[u].w), __fmul_rn(2.0f, acc));
    }
#pragma unroll
    for (int u = 0; u < 8; ++u) {
      float d2 = d2v[u];
      if (d2 < ld[15]) INSERT_CHAIN(d2, s + u);
    }
  }

  float thr = ld[15];        // stale-but-safe superset threshold
  int cnt = 0;               // this lane's buffer fill
  int bo = tid << 1;         // lane offset in a slot (2 floats: d2, j)

  // --- main scan: branchless filter, deferred exact replay ---
  for (int s = BOOT; s < NPTS; s += 8) {
    float4 p[8];
#pragma unroll
    for (int u = 0; u < 8; ++u) p[u] = s_p[s + u];
    float d2v[8];
#pragma unroll
    for (int u = 0; u < 8; ++u) {
      // V1 arithmetic, verbatim (BLAS FMA-chain dot, unfused combine)
      float acc = __fmul_rn(qx, p[u].x);
      acc = __fmaf_rn(qy, p[u].y, acc);
      acc = __fmaf_rn(qz, p[u].z, acc);
      d2v[u] = __fsub_rn(__fadd_rn(sqn, p[u].w), __fmul_rn(2.0f, acc));
    }
#pragma unroll
    for (int u = 0; u < 8; ++u) {
      // Unconditional write (slot is only consumed if cnt advances);
      // adjacent b32 pair, 8B-aligned -> ds_write_b64, 2-way bank alias (free).
      s_buf[cnt*128 + bo]     = d2v[u];
      s_buf[cnt*128 + bo + 1] = __int_as_float(s + u);
      cnt += (d2v[u] < thr) ? 1 : 0;
    }
    if (__ballot(cnt >= TRIG) != 0ULL) REPLAY();
  }
  REPLAY();   // final flush

  int* outp = idx_out + (b*NPTS + n)*KNN;
#pragma unroll
  for (int u = 0; u < 16; ++u) outp[u] = b*NPTS + lj[u];   // GLOBAL row index
}

// ---------------------------------------------------------------------------
// Fused layer: r5 structure (known-good), + LDS staging of a_w1/a_w2/p_w2
// (identical accumulation order => bit-identical output), t2 aliased onto
// s_win storage. ~52 KB LDS => 3 blocks/CU.  [UNTOUCHED this round]
// ---------------------------------------------------------------------------
__global__ __launch_bounds__(256) void fuse_kernel(
    const float* __restrict__ pos, const int* __restrict__ idx,
    const float* __restrict__ qf, const float* __restrict__ kf,
    const float* __restrict__ vf,
    const float* __restrict__ p_w1, const float* __restrict__ p_b1,
    const float* __restrict__ p_g, const float* __restrict__ p_be,
    const float* __restrict__ p_w2, const float* __restrict__ p_b2,
    const float* __restrict__ a_w1, const float* __restrict__ a_b1,
    const float* __restrict__ a_g, const float* __restrict__ a_be,
    const float* __restrict__ a_w2, const float* __restrict__ a_b2,
    float* __restrict__ out) {
  __shared__ int   s_j[16];
  __shared__ float s_h[16][12];
  __shared__ float s_win[16][64];     // reused as t2 after step 3
  __shared__ float s_ve[16][64];
  __shared__ float s_ai[16][64];
  __shared__ float s_act[16][64];
  __shared__ float s_m[16], s_rs[16];
  __shared__ float s_w1[4096];        // a_w1 [i][c]
  __shared__ float s_w2[4096];        // a_w2 [i][c]
  __shared__ float s_pw2[768];        // p_w2 [h][c]

  int tid = threadIdx.x;
  int p = blockIdx.x;

  for (int e = tid; e < 4096; e += 256) { s_w1[e] = a_w1[e]; s_w2[e] = a_w2[e]; }
  for (int e = tid; e < 768; e += 256) s_pw2[e] = p_w2[e];

  if (tid < 16) {
    int j = idx[p*KNN + tid];
    s_j[tid] = j;
    float rx = pos[p*3+0] - pos[j*3+0];
    float ry = pos[p*3+1] - pos[j*3+1];
    float rz = pos[p*3+2] - pos[j*3+2];
    float hv[12];
    float mean = 0.f;
#pragma unroll
    for (int h = 0; h < 12; ++h) {
      float v = rx*p_w1[h] + ry*p_w1[12+h] + rz*p_w1[24+h] + p_b1[h];
      hv[h] = v; mean += v;
    }
    mean *= (1.0f/12.0f);
    float var = 0.f;
#pragma unroll
    for (int h = 0; h < 12; ++h) { float d = hv[h] - mean; var += d*d; }
    var *= (1.0f/12.0f);
    float rs = rsqrtf(var + LN_EPS);
#pragma unroll
    for (int h = 0; h < 12; ++h) {
      float a = (hv[h] - mean)*rs*p_g[h] + p_be[h];
      s_h[tid][h] = fmaxf(a, 0.f);
    }
  }
  __syncthreads();

  int c = tid & 63, kq = tid >> 6;

  {
    float qv = qf[p*64 + c];
#pragma unroll
    for (int it = 0; it < 4; ++it) {
      int k = it*4 + kq;
      int j = s_j[k];
      float pe = p_b2[c];
#pragma unroll
      for (int h = 0; h < 12; ++h) pe += s_h[k][h] * s_pw2[h*64 + c];
      s_win[k][c] = qv - kf[j*64 + c] + pe;
      s_ve[k][c]  = vf[j*64 + c] + pe;
    }
  }
  __syncthreads();

#pragma unroll
  for (int it = 0; it < 4; ++it) {
    int k = it*4 + kq;
    float s = a_b1[c];
    for (int i = 0; i < 64; ++i) s += s_win[k][i] * s_w1[i*64 + c];
    s_ai[k][c] = s;
  }
  __syncthreads();

  if (tid < 16) {
    float m = 0.f;
    for (int c2 = 0; c2 < 64; ++c2) m += s_ai[tid][c2];
    m *= (1.0f/64.0f);
    float v = 0.f;
    for (int c2 = 0; c2 < 64; ++c2) { float d = s_ai[tid][c2] - m; v += d*d; }
    v *= (1.0f/64.0f);
    s_m[tid] = m; s_rs[tid] = rsqrtf(v + LN_EPS);
  }
  __syncthreads();
#pragma unroll
  for (int it = 0; it < 4; ++it) {
    int k = it*4 + kq;
    s_act[k][c] = fmaxf((s_ai[k][c] - s_m[k])*s_rs[k]*a_g[c] + a_be[c], 0.f);
  }
  __syncthreads();

  // t2 into s_win storage (s_win dead after step 3)
#pragma unroll
  for (int it = 0; it < 4; ++it) {
    int k = it*4 + kq;
    float s = a_b2[c];
    for (int i = 0; i < 64; ++i) s += s_act[k][i] * s_w2[i*64 + c];
    s_win[k][c] = s;
  }
  __syncthreads();

  if (tid < 64) {
    float mx = -INFINITY;
    for (int k = 0; k < 16; ++k) mx = fmaxf(mx, s_win[k][tid]);
    float se = 0.f, po = 0.f;
    for (int k = 0; k < 16; ++k) {
      float e = expf(s_win[k][tid] - mx);
      se += e; po += e * s_ve[k][tid];
    }
    out[p*64 + tid] = po / se;
  }
}

// ---------------------------------------------------------------------------
extern "C" void kernel_launch(void* const* d_in, const int* in_sizes, int n_in,
                              void* d_out, int out_size, void* d_ws, size_t ws_size,
                              hipStream_t stream) {
  const float* x    = (const float*)d_in[0];
  const float* pos  = (const float*)d_in[1];
  const float* Wq   = (const float*)d_in[2];
  const float* Wk   = (const float*)d_in[3];
  const float* Wv   = (const float*)d_in[4];
  const float* p_w1 = (const float*)d_in[5];
  const float* p_b1 = (const float*)d_in[6];
  const float* p_g  = (const float*)d_in[7];
  const float* p_be = (const float*)d_in[8];
  const float* p_w2 = (const float*)d_in[9];
  const float* p_b2 = (const float*)d_in[10];
  const float* a_w1 = (const float*)d_in[11];
  const float* a_b1 = (const float*)d_in[12];
  const float* a_g  = (const float*)d_in[13];
  const float* a_be = (const float*)d_in[14];
  const float* a_w2 = (const float*)d_in[15];
  const float* a_b2 = (const float*)d_in[16];

  float* ws   = (float*)d_ws;
  float* qf   = ws;                    // 1048576 floats
  float* kf   = qf + 1048576;          // 1048576
  float* vf   = kf + 1048576;          // 1048576
  int*   idx  = (int*)(vf + 1048576);  // 262144 ints
  float* outp = (float*)d_out;

  hipLaunchKernelGGL(proj3_kernel, dim3(4096), dim3(256), 0, stream,
                     x, Wq, Wk, Wv, qf, kf, vf);
  hipLaunchKernelGGL(knn_filter_replay_kernel, dim3(64, 4), dim3(64), 0, stream,
                     pos, idx);
  hipLaunchKernelGGL(fuse_kernel, dim3(16384), dim3(256), 0, stream,
                     pos, idx, qf, kf, vf,
                     p_w1, p_b1, p_g, p_be, p_w2, p_b2,
                     a_w1, a_b1, a_g, a_be, a_w2, a_b2, outp);
}

// Round 2
// 662.716 us; speedup vs baseline: 1.5478x; 1.0525x over previous
//
#include <hip/hip_runtime.h>
#include <math.h>

#define NPTS 4096
#define KNN 16
#define LN_EPS 1e-5f

// KNN tuning
#define BOOT 128    // exact serial bootstrap length (both waves, redundant, identical)
#define CAP0 32     // wave-0 replayable buffer slots
#define CAP1 144    // wave-1 hold-all buffer slots (expected max-lane ~90)
#define TRIG 24     // wave-0 replay trigger
#define HALF 2048   // candidate split point

// ---------------------------------------------------------------------------
// FROZEN ORACLE (r17 PASS, r19 falsified stable-top16): np's neighbor sets
// are reproduced by the r17 SERIAL algorithm exactly:
//   d2: sq=(x2+y2)+z2 seq; dot=fma(z,z',fma(y,y',x*x')); d2=(sqn+sqm)-(2*dot)
//   selection: ascending-j scan, admission `d2 < ld[15]` (strict, d2-only),
//   16-deep displaced-carry insert chain comparing d2 ONLY.
// NOTE: the chain is NOT stable for equal d2 — a displaced carry hops over an
// equal element, rotating equal runs ("scramble"). Hence TRANSIENT admissions
// matter and the filter threshold must dominate ld[15](j) at every j, not just
// the final d16. DO NOT modify admission/insert semantics.
//
// r22 (this round): 2-wave candidate split. Wave 0 = exact r21 filter+replay
// over [BOOT,HALF), publishing exact ld[15] to s_thr after each replay.
// Wave 1 concurrently filters [HALF,NPTS) with thr = min(boot thr, published)
// — valid superset since published = ld15(pos0), pos0 <= HALF <= j, and ld15
// is non-increasing. Wave 0 then replays wave-1's buffer ascending-j with the
// verbatim chain => bit-identical final state. Overflow flag + exact serial
// fallback makes correctness unconditional.
// ---------------------------------------------------------------------------

__global__ __launch_bounds__(256) void proj3_kernel(
    const float* __restrict__ x, const float* __restrict__ Wq,
    const float* __restrict__ Wk, const float* __restrict__ Wv,
    float* __restrict__ qf, float* __restrict__ kf, float* __restrict__ vf) {
  int g = blockIdx.x * 256 + threadIdx.x;
  int r = g >> 6, c = g & 63;
  float sq = 0.f, sk = 0.f, sv = 0.f;
  for (int i = 0; i < 64; ++i) {
    float xv = x[r*64 + i];
    sq += xv * Wq[i*64 + c];
    sk += xv * Wk[i*64 + c];
    sv += xv * Wv[i*64 + c];
  }
  qf[g] = sq; kf[g] = sk; vf[g] = sv;
}

// Verbatim r17 displaced-carry insert chain (frozen oracle — do not touch).
#define INSERT_CHAIN(DD, JJ)                                          \
  do {                                                                \
    float dd = (DD); int jj = (JJ);                                   \
    _Pragma("unroll")                                                 \
    for (int v = 0; v < 16; ++v) {                                    \
      bool sw = dd < ld[v];                                           \
      float nd = sw ? dd : ld[v]; float td = sw ? ld[v] : dd;         \
      int   nj = sw ? jj : lj[v]; int   tj = sw ? lj[v] : jj;         \
      ld[v] = nd; lj[v] = nj; dd = td; jj = tj;                       \
    }                                                                 \
  } while (0)

// Wave-0 replay: pop buffered candidates in ascending-j (push) order with the
// EXACT evolving admission, then tighten + publish the threshold.
#define REPLAY0()                                                     \
  do {                                                                \
    for (int i = 0; ; ++i) {                                          \
      unsigned long long alive = __ballot(i < cnt);                   \
      if (!alive) break;                                              \
      if (i < cnt) {                                                  \
        float dd0 = s_buf0[i*128 + bo];                               \
        int   jj0 = __float_as_int(s_buf0[i*128 + bo + 1]);           \
        if (dd0 < ld[15]) INSERT_CHAIN(dd0, jj0);                     \
      }                                                               \
    }                                                                 \
    cnt = 0; thr = ld[15]; s_thr[tid] = thr;                          \
  } while (0)

// One 8-candidate group: verbatim V1 d2 arithmetic.
#define GROUP_D2(SBASE)                                               \
  float4 p[8];                                                        \
  _Pragma("unroll")                                                   \
  for (int u = 0; u < 8; ++u) p[u] = s_p[(SBASE) + u];                \
  float d2v[8];                                                       \
  _Pragma("unroll")                                                   \
  for (int u = 0; u < 8; ++u) {                                       \
    float acc = __fmul_rn(qx, p[u].x);                                \
    acc = __fmaf_rn(qy, p[u].y, acc);                                 \
    acc = __fmaf_rn(qz, p[u].z, acc);                                 \
    d2v[u] = __fsub_rn(__fadd_rn(sqn, p[u].w), __fmul_rn(2.0f, acc)); \
  }

__global__ __launch_bounds__(128) void knn_split2_kernel(
    const float* __restrict__ pos, int* __restrict__ idx_out) {
  __shared__ __align__(16) float4 s_p[NPTS];        // 64 KB (x,y,z,sq)
  __shared__ __align__(16) float  s_buf0[CAP0*128]; // 16 KB wave-0 buffer
  __shared__ __align__(16) float  s_buf1[CAP1*128]; // 72 KB wave-1 buffer
  __shared__ float s_thr[64];                       // published exact ld15(pos0)
  __shared__ int   s_cnt1[64];
  __shared__ int   s_ovf;

  int t = threadIdx.x;
  int tid = t & 63, w = t >> 6, b = blockIdx.y;
  const float* pb = pos + b*NPTS*3;
  for (int j = t; j < NPTS; j += 128) {
    float px = pb[j*3+0], py = pb[j*3+1], pz = pb[j*3+2];
    float sq = __fadd_rn(__fadd_rn(__fmul_rn(px,px), __fmul_rn(py,py)),
                         __fmul_rn(pz,pz));
    s_p[j] = make_float4(px, py, pz, sq);
  }
  if (t < 64) s_thr[t] = INFINITY;
  if (t == 0) s_ovf = 0;
  __syncthreads();

  int n = blockIdx.x * 64 + tid;
  float4 qp = s_p[n];
  float qx = qp.x, qy = qp.y, qz = qp.z, sqn = qp.w;
  float ld[16]; int lj[16];
#pragma unroll
  for (int u = 0; u < 16; ++u) { ld[u] = INFINITY; lj[u] = 0x7fffffff; }

  // --- exact bootstrap [0, BOOT): both waves run identically (deterministic) ---
  for (int s = 0; s < BOOT; s += 8) {
    GROUP_D2(s)
#pragma unroll
    for (int u = 0; u < 8; ++u) {
      float d2 = d2v[u];
      if (d2 < ld[15]) INSERT_CHAIN(d2, s + u);
    }
  }
  float thr = ld[15];
  int bo = tid << 1;

  if (w == 0) {
    // --- wave 0: exact filter+replay over [BOOT, HALF) (r21 semantics) ---
    int cnt = 0;
    for (int s = BOOT; s < HALF; s += 8) {
      GROUP_D2(s)
#pragma unroll
      for (int u = 0; u < 8; ++u) {
        s_buf0[cnt*128 + bo]     = d2v[u];
        s_buf0[cnt*128 + bo + 1] = __int_as_float(s + u);
        cnt += (d2v[u] < thr) ? 1 : 0;
      }
      if (__ballot(cnt >= TRIG) != 0ULL) REPLAY0();
    }
    REPLAY0();          // state now == exact serial through j < HALF
    __syncthreads();    // wave 1 finished buffering

    if (s_ovf) {
      // exact serial fallback over [HALF, NPTS)
      for (int s = HALF; s < NPTS; s += 8) {
        GROUP_D2(s)
#pragma unroll
        for (int u = 0; u < 8; ++u) {
          s_buf0[cnt*128 + bo]     = d2v[u];
          s_buf0[cnt*128 + bo + 1] = __int_as_float(s + u);
          cnt += (d2v[u] < thr) ? 1 : 0;
        }
        if (__ballot(cnt >= TRIG) != 0ULL) REPLAY0();
      }
      REPLAY0();
    } else {
      // merge-replay wave-1's buffer (ascending j, exact admission)
      int c1 = s_cnt1[tid];
      for (int i = 0; ; ++i) {
        unsigned long long alive = __ballot(i < c1);
        if (!alive) break;
        if (i < c1) {
          float dd0 = s_buf1[i*128 + bo];
          int   jj0 = __float_as_int(s_buf1[i*128 + bo + 1]);
          if (dd0 < ld[15]) INSERT_CHAIN(dd0, jj0);
        }
      }
    }
    int* outp = idx_out + (b*NPTS + n)*KNN;
#pragma unroll
    for (int u = 0; u < 16; ++u) outp[u] = b*NPTS + lj[u];   // GLOBAL row index
  } else {
    // --- wave 1: superset filter over [HALF, NPTS), no replays ---
    int cnt = 0;
    float thrW = thr;
    for (int s = HALF; s < NPTS; s += 8) {
      thrW = fminf(thrW, *(volatile float*)&s_thr[tid]);   // stale = still valid
      GROUP_D2(s)
#pragma unroll
      for (int u = 0; u < 8; ++u) {
        if (cnt < CAP1) {
          s_buf1[cnt*128 + bo]     = d2v[u];
          s_buf1[cnt*128 + bo + 1] = __int_as_float(s + u);
        }
        cnt += (d2v[u] < thrW) ? 1 : 0;
      }
    }
    s_cnt1[tid] = (cnt > CAP1) ? CAP1 : cnt;
    if (cnt > CAP1) s_ovf = 1;    // benign race: any writer sets 1
    __syncthreads();
  }
}

// ---------------------------------------------------------------------------
// Fused layer r22: transposed+XOR-swizzled weight tiles read as ds_read_b128,
// it-blocked matmuls (each weight granule read once), LN via 64-lane shfl_xor
// butterflies on in-register accumulators (removes serial LN section, its
// 16-way bank conflicts, s_ai/s_m/s_rs, and 2 barriers). Per-output i-order
// of FMA accumulation is unchanged (ascending); only LN reductions reassociate
// (~1e-6, far under tolerance). ~48 KB LDS => 3 blocks/CU.
// ---------------------------------------------------------------------------
__device__ __forceinline__ float wsum64(float v) {
  v += __shfl_xor(v, 1);
  v += __shfl_xor(v, 2);
  v += __shfl_xor(v, 4);
  v += __shfl_xor(v, 8);
  v += __shfl_xor(v, 16);
  v += __shfl_xor(v, 32);
  return v;
}

__global__ __launch_bounds__(256) void fuse_kernel(
    const float* __restrict__ pos, const int* __restrict__ idx,
    const float* __restrict__ qf, const float* __restrict__ kf,
    const float* __restrict__ vf,
    const float* __restrict__ p_w1, const float* __restrict__ p_b1,
    const float* __restrict__ p_g, const float* __restrict__ p_be,
    const float* __restrict__ p_w2, const float* __restrict__ p_b2,
    const float* __restrict__ a_w1, const float* __restrict__ a_b1,
    const float* __restrict__ a_g, const float* __restrict__ a_be,
    const float* __restrict__ a_w2, const float* __restrict__ a_b2,
    float* __restrict__ out) {
  __shared__ int   s_j[16];
  __shared__ float s_h[16][12];
  __shared__ __align__(16) float s_win[16][64];   // win, later t2
  __shared__ __align__(16) float s_ve[16][64];
  __shared__ __align__(16) float s_act[16][64];
  __shared__ float s_pw2[768];                    // p_w2 [h][c]
  __shared__ __align__(16) float s_w1t[64][64];   // a_w1 transposed [c][i], XOR-swizzled granules
  __shared__ __align__(16) float s_w2t[64][64];   // a_w2 likewise

  int tid = threadIdx.x;
  int p = blockIdx.x;
  int c = tid & 63, kq = tid >> 6;

  // stage transposed + granule-swizzled weights (coalesced global reads)
  for (int e = tid; e < 4096; e += 256) {
    int i = e >> 6, cc = e & 63;
    int g = i >> 2, go = i & 3;
    int gs = g ^ (cc & 15);
    s_w1t[cc][4*gs + go] = a_w1[e];
    s_w2t[cc][4*gs + go] = a_w2[e];
  }
  for (int e = tid; e < 768; e += 256) s_pw2[e] = p_w2[e];

  if (tid < 16) {
    int j = idx[p*KNN + tid];
    s_j[tid] = j;
    float rx = pos[p*3+0] - pos[j*3+0];
    float ry = pos[p*3+1] - pos[j*3+1];
    float rz = pos[p*3+2] - pos[j*3+2];
    float hv[12];
    float mean = 0.f;
#pragma unroll
    for (int h = 0; h < 12; ++h) {
      float v = rx*p_w1[h] + ry*p_w1[12+h] + rz*p_w1[24+h] + p_b1[h];
      hv[h] = v; mean += v;
    }
    mean *= (1.0f/12.0f);
    float var = 0.f;
#pragma unroll
    for (int h = 0; h < 12; ++h) { float d = hv[h] - mean; var += d*d; }
    var *= (1.0f/12.0f);
    float rs = rsqrtf(var + LN_EPS);
#pragma unroll
    for (int h = 0; h < 12; ++h) {
      float a = (hv[h] - mean)*rs*p_g[h] + p_be[h];
      s_h[tid][h] = fmaxf(a, 0.f);
    }
  }
  __syncthreads();

  // --- section 1: pos-enc + win/ve (h-outer loop: 1 pw2 read serves 4 k) ---
  {
    float qv = qf[p*64 + c];
    float pb2 = p_b2[c];
    float pe0 = pb2, pe1 = pb2, pe2 = pb2, pe3 = pb2;
#pragma unroll
    for (int h = 0; h < 12; ++h) {
      float wv = s_pw2[h*64 + c];
      pe0 = __fmaf_rn(s_h[kq][h],    wv, pe0);
      pe1 = __fmaf_rn(s_h[4+kq][h],  wv, pe1);
      pe2 = __fmaf_rn(s_h[8+kq][h],  wv, pe2);
      pe3 = __fmaf_rn(s_h[12+kq][h], wv, pe3);
    }
    int j0 = s_j[kq], j1 = s_j[4+kq], j2 = s_j[8+kq], j3 = s_j[12+kq];
    s_win[kq][c]    = qv - kf[j0*64 + c] + pe0;  s_ve[kq][c]    = vf[j0*64 + c] + pe0;
    s_win[4+kq][c]  = qv - kf[j1*64 + c] + pe1;  s_ve[4+kq][c]  = vf[j1*64 + c] + pe1;
    s_win[8+kq][c]  = qv - kf[j2*64 + c] + pe2;  s_ve[8+kq][c]  = vf[j2*64 + c] + pe2;
    s_win[12+kq][c] = qv - kf[j3*64 + c] + pe3;  s_ve[12+kq][c] = vf[j3*64 + c] + pe3;
  }
  __syncthreads();

  int swz = c & 15;

  // --- step 3: ai = win @ a_w1 + b1; fused LN(butterfly) + ReLU -> s_act ---
  {
    float ab1 = a_b1[c];
    float a0 = ab1, a1 = ab1, a2 = ab1, a3 = ab1;
    const float* w1r = &s_w1t[c][0];
#pragma unroll
    for (int ii = 0; ii < 16; ++ii) {
      float4 wa = *(const float4*)(w1r + 4*(ii ^ swz));
      float4 x0 = *(const float4*)(&s_win[kq][4*ii]);
      float4 x1 = *(const float4*)(&s_win[4+kq][4*ii]);
      float4 x2 = *(const float4*)(&s_win[8+kq][4*ii]);
      float4 x3 = *(const float4*)(&s_win[12+kq][4*ii]);
      a0 = __fmaf_rn(x0.x, wa.x, a0); a0 = __fmaf_rn(x0.y, wa.y, a0);
      a0 = __fmaf_rn(x0.z, wa.z, a0); a0 = __fmaf_rn(x0.w, wa.w, a0);
      a1 = __fmaf_rn(x1.x, wa.x, a1); a1 = __fmaf_rn(x1.y, wa.y, a1);
      a1 = __fmaf_rn(x1.z, wa.z, a1); a1 = __fmaf_rn(x1.w, wa.w, a1);
      a2 = __fmaf_rn(x2.x, wa.x, a2); a2 = __fmaf_rn(x2.y, wa.y, a2);
      a2 = __fmaf_rn(x2.z, wa.z, a2); a2 = __fmaf_rn(x2.w, wa.w, a2);
      a3 = __fmaf_rn(x3.x, wa.x, a3); a3 = __fmaf_rn(x3.y, wa.y, a3);
      a3 = __fmaf_rn(x3.z, wa.z, a3); a3 = __fmaf_rn(x3.w, wa.w, a3);
    }
    float ag = a_g[c], abe = a_be[c];
#pragma unroll
    for (int it = 0; it < 4; ++it) {
      float v = (it == 0) ? a0 : (it == 1) ? a1 : (it == 2) ? a2 : a3;
      float m = wsum64(v) * (1.0f/64.0f);
      float d = v - m;
      float var = wsum64(d*d) * (1.0f/64.0f);
      float rs = rsqrtf(var + LN_EPS);
      s_act[it*4 + kq][c] = fmaxf(d*rs*ag + abe, 0.f);
    }
  }
  __syncthreads();

  // --- t2 = act @ a_w2 + b2 -> s_win (dead storage) ---
  {
    float ab2 = a_b2[c];
    float a0 = ab2, a1 = ab2, a2 = ab2, a3 = ab2;
    const float* w2r = &s_w2t[c][0];
#pragma unroll
    for (int ii = 0; ii < 16; ++ii) {
      float4 wa = *(const float4*)(w2r + 4*(ii ^ swz));
      float4 x0 = *(const float4*)(&s_act[kq][4*ii]);
      float4 x1 = *(const float4*)(&s_act[4+kq][4*ii]);
      float4 x2 = *(const float4*)(&s_act[8+kq][4*ii]);
      float4 x3 = *(const float4*)(&s_act[12+kq][4*ii]);
      a0 = __fmaf_rn(x0.x, wa.x, a0); a0 = __fmaf_rn(x0.y, wa.y, a0);
      a0 = __fmaf_rn(x0.z, wa.z, a0); a0 = __fmaf_rn(x0.w, wa.w, a0);
      a1 = __fmaf_rn(x1.x, wa.x, a1); a1 = __fmaf_rn(x1.y, wa.y, a1);
      a1 = __fmaf_rn(x1.z, wa.z, a1); a1 = __fmaf_rn(x1.w, wa.w, a1);
      a2 = __fmaf_rn(x2.x, wa.x, a2); a2 = __fmaf_rn(x2.y, wa.y, a2);
      a2 = __fmaf_rn(x2.z, wa.z, a2); a2 = __fmaf_rn(x2.w, wa.w, a2);
      a3 = __fmaf_rn(x3.x, wa.x, a3); a3 = __fmaf_rn(x3.y, wa.y, a3);
      a3 = __fmaf_rn(x3.z, wa.z, a3); a3 = __fmaf_rn(x3.w, wa.w, a3);
    }
    s_win[kq][c]    = a0;
    s_win[4+kq][c]  = a1;
    s_win[8+kq][c]  = a2;
    s_win[12+kq][c] = a3;
  }
  __syncthreads();

  if (tid < 64) {
    float mx = -INFINITY;
    for (int k = 0; k < 16; ++k) mx = fmaxf(mx, s_win[k][tid]);
    float se = 0.f, po = 0.f;
    for (int k = 0; k < 16; ++k) {
      float e = expf(s_win[k][tid] - mx);
      se += e; po += e * s_ve[k][tid];
    }
    out[p*64 + tid] = po / se;
  }
}

// ---------------------------------------------------------------------------
extern "C" void kernel_launch(void* const* d_in, const int* in_sizes, int n_in,
                              void* d_out, int out_size, void* d_ws, size_t ws_size,
                              hipStream_t stream) {
  const float* x    = (const float*)d_in[0];
  const float* pos  = (const float*)d_in[1];
  const float* Wq   = (const float*)d_in[2];
  const float* Wk   = (const float*)d_in[3];
  const float* Wv   = (const float*)d_in[4];
  const float* p_w1 = (const float*)d_in[5];
  const float* p_b1 = (const float*)d_in[6];
  const float* p_g  = (const float*)d_in[7];
  const float* p_be = (const float*)d_in[8];
  const float* p_w2 = (const float*)d_in[9];
  const float* p_b2 = (const float*)d_in[10];
  const float* a_w1 = (const float*)d_in[11];
  const float* a_b1 = (const float*)d_in[12];
  const float* a_g  = (const float*)d_in[13];
  const float* a_be = (const float*)d_in[14];
  const float* a_w2 = (const float*)d_in[15];
  const float* a_b2 = (const float*)d_in[16];

  float* ws   = (float*)d_ws;
  float* qf   = ws;                    // 1048576 floats
  float* kf   = qf + 1048576;          // 1048576
  float* vf   = kf + 1048576;          // 1048576
  int*   idx  = (int*)(vf + 1048576);  // 262144 ints
  float* outp = (float*)d_out;

  hipLaunchKernelGGL(proj3_kernel, dim3(4096), dim3(256), 0, stream,
                     x, Wq, Wk, Wv, qf, kf, vf);
  hipLaunchKernelGGL(knn_split2_kernel, dim3(64, 4), dim3(128), 0, stream,
                     pos, idx);
  hipLaunchKernelGGL(fuse_kernel, dim3(16384), dim3(256), 0, stream,
                     pos, idx, qf, kf, vf,
                     p_w1, p_b1, p_g, p_be, p_w2, p_b2,
                     a_w1, a_b1, a_g, a_be, a_w2, a_b2, outp);
}